// Round 1
// baseline (487.779 us; speedup 1.0000x reference)
//
#include <hip/hip_runtime.h>

// Erosion2D: x (8,512,512,32) f32 NHWC, w (4,4,32) f32, SAME, stride 1.
// out[b,y,x,c] = min_{dy,dx in [0,4)} xp[b, y+dy-1, x+dx-1, c] - w[3-dy, 3-dx, c]
// OOB padded with 1e30 (matches reference BIG).

#define BIGV 1e30f

__global__ __launch_bounds__(256) void erosion_kernel(
    const float* __restrict__ x, const float* __restrict__ w,
    float* __restrict__ out)
{
    constexpr int H = 512, W = 512, C = 32;
    constexpr int TX = 32;        // output x-pixels per block
    constexpr int YC = 64;        // output rows per block
    constexpr int LP = TX + 3;    // 35 input pixels per LDS row (x-halo)
    constexpr int LSTRIDE = 36;   // padded pixel stride in LDS

    // 4-row ring buffer: 4 * 36 * 32 floats * 4 B = 18432 B
    __shared__ float lds[4 * LSTRIDE * C];

    const int tid = threadIdx.x;
    const int c4  = tid & 7;      // channel quad: channels c4*4 .. c4*4+3
    const int xi  = tid >> 3;     // 0..31 output pixel within tile
    const int x0  = blockIdx.x * TX;   // 16 x-tiles
    const int y0  = blockIdx.y * YC;   // 8 y-chunks
    const int b   = blockIdx.z;        // 8 batches

    // Preload reflected structuring element fragment: wv[dy][dx] = w[3-dy][3-dx][c4*4..]
    float4 wv[4][4];
    #pragma unroll
    for (int dy = 0; dy < 4; ++dy)
        #pragma unroll
        for (int dx = 0; dx < 4; ++dx)
            wv[dy][dx] = *(const float4*)(w + ((3 - dy) * 4 + (3 - dx)) * C + c4 * 4);

    const float4 big4 = make_float4(BIGV, BIGV, BIGV, BIGV);

    auto load_row = [&](int r) {
        float4* dst = (float4*)(lds + (r & 3) * LSTRIDE * C);
        const bool rvalid = (r >= 0 && r < H);
        // 35 pixels * 8 quads = 280 float4 stores; 256 threads -> <=2 each
        for (int li = tid; li < LP * 8; li += 256) {
            const int px = li >> 3;
            const int cc = li & 7;
            const int gx = x0 - 1 + px;
            float4 v = big4;
            if (rvalid && gx >= 0 && gx < W)
                v = *(const float4*)(x + (((size_t)(b * H + r)) * W + gx) * C + cc * 4);
            dst[px * 8 + cc] = v;
        }
    };

    // Prime ring with input rows y0-1, y0, y0+1 (slots r & 3)
    load_row(y0 - 1);
    load_row(y0);
    load_row(y0 + 1);

    for (int y = y0; y < y0 + YC; ++y) {
        load_row(y + 2);          // fetch bottom row of this output's window
        __syncthreads();          // make all 4 window rows visible

        float4 acc = big4;
        #pragma unroll
        for (int dy = 0; dy < 4; ++dy) {
            const float4* rowp =
                (const float4*)(lds + ((y + dy - 1) & 3) * LSTRIDE * C);
            #pragma unroll
            for (int dx = 0; dx < 4; ++dx) {
                const float4 v  = rowp[(xi + dx) * 8 + c4];
                const float4 wq = wv[dy][dx];
                acc.x = fminf(acc.x, v.x - wq.x);
                acc.y = fminf(acc.y, v.y - wq.y);
                acc.z = fminf(acc.z, v.z - wq.z);
                acc.w = fminf(acc.w, v.w - wq.w);
            }
        }

        *(float4*)(out + (((size_t)(b * H + y)) * W + (x0 + xi)) * C + c4 * 4) = acc;
        __syncthreads();          // compute done before next iter overwrites a slot
    }
}

extern "C" void kernel_launch(void* const* d_in, const int* in_sizes, int n_in,
                              void* d_out, int out_size, void* d_ws, size_t ws_size,
                              hipStream_t stream)
{
    const float* x = (const float*)d_in[0];
    const float* w = (const float*)d_in[1];
    float* out = (float*)d_out;

    dim3 grid(16, 8, 8);   // (x-tiles, y-chunks, batch)
    dim3 block(256);
    hipLaunchKernelGGL(erosion_kernel, grid, block, 0, stream, x, w, out);
}